// Round 1
// baseline (1090.962 us; speedup 1.0000x reference)
//
#include <hip/hip_runtime.h>
#include <math.h>

#define B_SZ 512
#define S_SZ 512
#define I_DIM 128
#define H_DIM 128
#define E_NUM 8
#define F_DIM 20
#define CHUNK 64

// ---------------- Kernel 1: x_mean + logits ----------------
__global__ __launch_bounds__(512) void k_mean_logits(
    const float* __restrict__ x, const float* __restrict__ w_gate,
    float* __restrict__ logits) {
  __shared__ float sm[512];
  __shared__ float xm[128];
  int b = blockIdx.x;
  int t = threadIdx.x;
  int i = t & 127, s0 = t >> 7;  // s0 in 0..3
  const float* xb = x + (size_t)b * (S_SZ * I_DIM);
  float acc = 0.f;
  for (int s = s0; s < S_SZ; s += 4) acc += xb[s * I_DIM + i];
  sm[t] = acc;
  __syncthreads();
  if (t < 128) {
    xm[t] = (sm[t] + sm[t + 128] + sm[t + 256] + sm[t + 384]) * (1.0f / 512.0f);
  }
  __syncthreads();
  if (t < E_NUM) {
    float acc2 = 0.f;
    for (int ii = 0; ii < 128; ii++) acc2 += xm[ii] * w_gate[ii * E_NUM + t];
    logits[b * E_NUM + t] = acc2;
  }
}

// ---------------- Kernel 2: top-2 gates + CV^2 loss ----------------
__global__ __launch_bounds__(512) void k_gate(
    const float* __restrict__ logits, int* __restrict__ sel_e,
    float* __restrict__ sel_g, float* __restrict__ loss_out) {
  __shared__ float gmat[512][8];
  __shared__ int cnt[8];
  __shared__ float imps[8];
  int t = threadIdx.x;
  if (t < 8) cnt[t] = 0;
  float lv[8];
#pragma unroll
  for (int e = 0; e < 8; e++) {
    lv[e] = logits[t * 8 + e];
    gmat[t][e] = 0.f;
  }
  __syncthreads();
  // top-2 (ties: earlier index wins, matching lax.top_k ordering)
  float v0 = -INFINITY, v1 = -INFINITY;
  int i0 = 0, i1 = 0;
#pragma unroll
  for (int e = 0; e < 8; e++) {
    float v = lv[e];
    if (v > v0) { v1 = v0; i1 = i0; v0 = v; i0 = e; }
    else if (v > v1) { v1 = v; i1 = e; }
  }
  float ex = expf(v1 - v0);
  float inv = 1.0f / (1.0f + ex);
  float g0 = inv, g1 = ex * inv;
  gmat[t][i0] = g0;
  gmat[t][i1] = g1;
  atomicAdd(&cnt[i0], 1);
  atomicAdd(&cnt[i1], 1);
  sel_e[t * 2] = i0; sel_e[t * 2 + 1] = i1;
  sel_g[t * 2] = g0; sel_g[t * 2 + 1] = g1;
  __syncthreads();
  if (t < 8) {  // deterministic serial column sum
    float s = 0.f;
    for (int bb = 0; bb < 512; bb++) s += gmat[bb][t];
    imps[t] = s;
  }
  __syncthreads();
  if (t == 0) {
    float mi = 0.f, ml = 0.f;
#pragma unroll
    for (int e = 0; e < 8; e++) { mi += imps[e]; ml += (float)cnt[e]; }
    mi *= 0.125f; ml *= 0.125f;
    float vi = 0.f, vl = 0.f;
#pragma unroll
    for (int e = 0; e < 8; e++) {
      float di = imps[e] - mi; vi += di * di;
      float dl = (float)cnt[e] - ml; vl += dl * dl;
    }
    vi *= (1.0f / 7.0f);  // ddof=1
    vl *= (1.0f / 7.0f);
    loss_out[0] = 0.01f * (vi / (mi * mi + 1e-10f) + vl / (ml * ml + 1e-10f));
  }
}

// ---------------- Kernel 3: per-(batch,slot) RNN + MLP head ----------------
// One block per selected (batch, expert) pair. W_ih/W_hh slices in VGPRs,
// h broadcast from LDS, x streamed in 64-step chunks.
__global__ __launch_bounds__(256, 2) void k_rnn(
    const float* __restrict__ x, const float* __restrict__ W_ih,
    const float* __restrict__ W_hh, const float* __restrict__ b_ih,
    const float* __restrict__ b_hh, const float* __restrict__ fc1_w,
    const float* __restrict__ fc1_b, const float* __restrict__ fc2_w,
    const float* __restrict__ fc2_b, const int* __restrict__ sel_e,
    float* __restrict__ outp) {
  __shared__ float xbuf[CHUNK * 128];
  __shared__ float hbuf[2][128];
  __shared__ float zbuf[F_DIM];
  int p = blockIdx.x;
  int b = p >> 1;
  int t = threadIdx.x;
  int e = sel_e[p];
  int o = t >> 1, half = t & 1;

  // W_ih[e][o][half*64 + j] flat = e*16384 + t*64 + j  (same for W_hh)
  float wih[64], whh[64];
  const float4* wi4 = (const float4*)(W_ih + (size_t)e * 16384 + (size_t)t * 64);
  const float4* wh4 = (const float4*)(W_hh + (size_t)e * 16384 + (size_t)t * 64);
#pragma unroll
  for (int k = 0; k < 16; k++) {
    float4 a = wi4[k];
    wih[4 * k] = a.x; wih[4 * k + 1] = a.y; wih[4 * k + 2] = a.z; wih[4 * k + 3] = a.w;
    float4 c = wh4[k];
    whh[4 * k] = c.x; whh[4 * k + 1] = c.y; whh[4 * k + 2] = c.z; whh[4 * k + 3] = c.w;
  }
  float bias = b_ih[e * 128 + o] + b_hh[e * 128 + o];
  if (t < 128) { hbuf[0][t] = 0.f; hbuf[1][t] = 0.f; }

  const float* xb = x + (size_t)b * (S_SZ * 128);
  int cur = 0;
#pragma unroll 1
  for (int c = 0; c < S_SZ / CHUNK; c++) {
    __syncthreads();  // previous chunk fully consumed (also covers hbuf init)
    const float4* src = (const float4*)(xb + (size_t)c * CHUNK * 128);
    float4* dst = (float4*)xbuf;
#pragma unroll
    for (int k = 0; k < (CHUNK * 128 / 4 / 256); k++) dst[t + k * 256] = src[t + k * 256];
    __syncthreads();
#pragma unroll 1
    for (int s = 0; s < CHUNK; s++) {
      const float* xrow = &xbuf[s * 128 + half * 64];
      const float* hrow = &hbuf[cur][half * 64];
      float a0 = 0.f, a1 = 0.f, a2 = 0.f, a3 = 0.f;
#pragma unroll
      for (int j = 0; j < 64; j += 4) {
        float4 xv = *(const float4*)(xrow + j);
        float4 hv = *(const float4*)(hrow + j);
        a0 = fmaf(wih[j], xv.x, a0);     a0 = fmaf(whh[j], hv.x, a0);
        a1 = fmaf(wih[j + 1], xv.y, a1); a1 = fmaf(whh[j + 1], hv.y, a1);
        a2 = fmaf(wih[j + 2], xv.z, a2); a2 = fmaf(whh[j + 2], hv.z, a2);
        a3 = fmaf(wih[j + 3], xv.w, a3); a3 = fmaf(whh[j + 3], hv.w, a3);
      }
      float part = (a0 + a1) + (a2 + a3);
      float other = __shfl_xor(part, 1, 64);
      if (half == 0) hbuf[cur ^ 1][o] = tanhf(part + other + bias);
      __syncthreads();
      cur ^= 1;
    }
  }
  // MLP head: z = tanh(hT @ fc1_w^T + fc1_b); out = z @ fc2_w^T + fc2_b
  if (t < 8 * F_DIM) {
    int f = t >> 3, j0 = (t & 7) * 16;
    const float* w1 = fc1_w + (size_t)e * (F_DIM * 128) + f * 128 + j0;
    const float* hr = &hbuf[cur][j0];
    float acc = 0.f;
#pragma unroll
    for (int j = 0; j < 16; j++) acc = fmaf(hr[j], w1[j], acc);
    acc += __shfl_xor(acc, 1, 64);
    acc += __shfl_xor(acc, 2, 64);
    acc += __shfl_xor(acc, 4, 64);
    if ((t & 7) == 0) zbuf[f] = tanhf(acc + fc1_b[e * F_DIM + f]);
  }
  __syncthreads();
  if (t == 0) {
    float acc = fc2_b[e];
#pragma unroll
    for (int f = 0; f < F_DIM; f++) acc = fmaf(zbuf[f], fc2_w[e * F_DIM + f], acc);
    outp[p] = acc;
  }
}

// ---------------- Kernel 4: weighted combine ----------------
__global__ void k_combine(const float* __restrict__ sel_g,
                          const float* __restrict__ outp,
                          float* __restrict__ y) {
  int b = blockIdx.x * blockDim.x + threadIdx.x;
  if (b < B_SZ)
    y[b] = sel_g[2 * b] * outp[2 * b] + sel_g[2 * b + 1] * outp[2 * b + 1];
}

extern "C" void kernel_launch(void* const* d_in, const int* in_sizes, int n_in,
                              void* d_out, int out_size, void* d_ws,
                              size_t ws_size, hipStream_t stream) {
  (void)in_sizes; (void)n_in; (void)out_size; (void)ws_size;
  const float* x      = (const float*)d_in[0];
  const float* w_gate = (const float*)d_in[1];
  const float* W_ih   = (const float*)d_in[2];
  const float* W_hh   = (const float*)d_in[3];
  const float* b_ih   = (const float*)d_in[4];
  const float* b_hh   = (const float*)d_in[5];
  const float* fc1_w  = (const float*)d_in[6];
  const float* fc1_b  = (const float*)d_in[7];
  const float* fc2_w  = (const float*)d_in[8];
  const float* fc2_b  = (const float*)d_in[9];
  float* out = (float*)d_out;  // [0..511] = y, [512] = loss

  float* logits = (float*)d_ws;             // 4096 f32
  int*   sel_e  = (int*)(logits + 4096);    // 1024 i32
  float* sel_g  = (float*)(sel_e + 1024);   // 1024 f32
  float* outp   = sel_g + 1024;             // 1024 f32

  k_mean_logits<<<B_SZ, 512, 0, stream>>>(x, w_gate, logits);
  k_gate<<<1, 512, 0, stream>>>(logits, sel_e, sel_g, out + 512);
  k_rnn<<<B_SZ * 2, 256, 0, stream>>>(x, W_ih, W_hh, b_ih, b_hh, fc1_w, fc1_b,
                                      fc2_w, fc2_b, sel_e, outp);
  k_combine<<<2, 256, 0, stream>>>(sel_g, outp, out);
}

// Round 2
// 819.414 us; speedup vs baseline: 1.3314x; 1.3314x over previous
//
#include <hip/hip_runtime.h>
#include <math.h>

#define B_SZ 512
#define S_SZ 512
#define E_NUM 8
#define F_DIM 20
#define BM 8          // pair-rows per RNN block
#define MAXBLK 136    // >= 8 + 1024/BM

typedef __attribute__((ext_vector_type(8))) short bf16x8;
typedef __attribute__((ext_vector_type(4))) float f32x4;
#define MFMA(a, b, c) __builtin_amdgcn_mfma_f32_16x16x32_bf16(a, b, c, 0, 0, 0)

__device__ __forceinline__ unsigned short f2bf(float f) {
  unsigned u = __float_as_uint(f);
  u += 0x7FFFu + ((u >> 16) & 1u);
  return (unsigned short)(u >> 16);
}
__device__ __forceinline__ float bf2f(unsigned short h) {
  return __uint_as_float(((unsigned)h) << 16);
}
__device__ __forceinline__ void cvt4(const float4 v, ushort4* hi, ushort4* lo) {
  hi->x = f2bf(v.x); hi->y = f2bf(v.y); hi->z = f2bf(v.z); hi->w = f2bf(v.w);
  lo->x = f2bf(v.x - bf2f(hi->x));
  lo->y = f2bf(v.y - bf2f(hi->y));
  lo->z = f2bf(v.z - bf2f(hi->z));
  lo->w = f2bf(v.w - bf2f(hi->w));
}

// ---------------- Kernel 1: x_mean + logits ----------------
__global__ __launch_bounds__(512) void k_mean_logits(
    const float* __restrict__ x, const float* __restrict__ w_gate,
    float* __restrict__ logits) {
  __shared__ float sm[512];
  __shared__ float xm[128];
  int b = blockIdx.x;
  int t = threadIdx.x;
  int i = t & 127, s0 = t >> 7;
  const float* xb = x + (size_t)b * (S_SZ * 128);
  float acc = 0.f;
  for (int s = s0; s < S_SZ; s += 4) acc += xb[s * 128 + i];
  sm[t] = acc;
  __syncthreads();
  if (t < 128)
    xm[t] = (sm[t] + sm[t + 128] + sm[t + 256] + sm[t + 384]) * (1.0f / 512.0f);
  __syncthreads();
  if (t < E_NUM) {
    float acc2 = 0.f;
    for (int ii = 0; ii < 128; ii++) acc2 += xm[ii] * w_gate[ii * E_NUM + t];
    logits[b * E_NUM + t] = acc2;
  }
}

// ------- Kernel 2: top-2 gates + CV^2 loss + expert compaction -------
__global__ __launch_bounds__(512) void k_gate(
    const float* __restrict__ logits, float* __restrict__ sel_g,
    int* __restrict__ pair_b, int* __restrict__ pair_of,
    int* __restrict__ blk_e, int* __restrict__ blk_p0,
    int* __restrict__ blk_nr, int* __restrict__ nblk,
    float* __restrict__ loss_out) {
  __shared__ float gmat[512][8];
  __shared__ int cnt[8], base[8], pos[8];
  __shared__ float imps[8];
  int t = threadIdx.x;
  if (t < 8) { cnt[t] = 0; pos[t] = 0; }
  float lv[8];
#pragma unroll
  for (int e = 0; e < 8; e++) {
    lv[e] = logits[t * 8 + e];
    gmat[t][e] = 0.f;
  }
  __syncthreads();
  float v0 = -INFINITY, v1 = -INFINITY;
  int i0 = 0, i1 = 0;
#pragma unroll
  for (int e = 0; e < 8; e++) {
    float v = lv[e];
    if (v > v0) { v1 = v0; i1 = i0; v0 = v; i0 = e; }
    else if (v > v1) { v1 = v; i1 = e; }
  }
  float ex = expf(v1 - v0);
  float inv = 1.0f / (1.0f + ex);
  float g0 = inv, g1 = ex * inv;
  gmat[t][i0] = g0;
  gmat[t][i1] = g1;
  atomicAdd(&cnt[i0], 1);
  atomicAdd(&cnt[i1], 1);
  sel_g[t * 2] = g0;
  sel_g[t * 2 + 1] = g1;
  __syncthreads();
  if (t == 0) {
    int o = 0;
    for (int e = 0; e < 8; e++) { base[e] = o; o += cnt[e]; }
    int nb = 0;
    for (int e = 0; e < 8; e++)
      for (int off = 0; off < cnt[e]; off += BM) {
        blk_e[nb] = e;
        blk_p0[nb] = base[e] + off;
        blk_nr[nb] = min(BM, cnt[e] - off);
        nb++;
      }
    *nblk = nb;
  }
  if (t < 8) {
    float s = 0.f;
    for (int bb = 0; bb < 512; bb++) s += gmat[bb][t];
    imps[t] = s;
  }
  __syncthreads();
  {
    int r = atomicAdd(&pos[i0], 1);
    int p = base[i0] + r;
    pair_b[p] = t;
    pair_of[t * 2] = p;
  }
  {
    int r = atomicAdd(&pos[i1], 1);
    int p = base[i1] + r;
    pair_b[p] = t;
    pair_of[t * 2 + 1] = p;
  }
  if (t == 0) {
    float mi = 0.f, ml = 0.f;
#pragma unroll
    for (int e = 0; e < 8; e++) { mi += imps[e]; ml += (float)cnt[e]; }
    mi *= 0.125f; ml *= 0.125f;
    float vi = 0.f, vl = 0.f;
#pragma unroll
    for (int e = 0; e < 8; e++) {
      float di = imps[e] - mi; vi += di * di;
      float dl = (float)cnt[e] - ml; vl += dl * dl;
    }
    vi *= (1.0f / 7.0f);
    vl *= (1.0f / 7.0f);
    loss_out[0] = 0.01f * (vi / (mi * mi + 1e-10f) + vl / (ml * ml + 1e-10f));
  }
}

// ---- stage a 128x128 fp32 matrix into swizzled bf16 hi/lo LDS tiles ----
__device__ __forceinline__ void stage_w(const float* __restrict__ W,
                                        unsigned short* dh,
                                        unsigned short* dl, int tid) {
#pragma unroll
  for (int it = 0; it < 8; it++) {
    int idx = tid + it * 256;
    int row = idx >> 4;
    int k0 = (idx & 15) << 3;
    const float* src = W + row * 128 + k0;
    float4 a = *(const float4*)src;
    float4 b = *(const float4*)(src + 4);
    int el = (row * 128 + k0) ^ ((row & 7) << 3);
    ushort4 h0, l0, h1, l1;
    cvt4(a, &h0, &l0);
    cvt4(b, &h1, &l1);
    *(ushort4*)&dh[el] = h0;
    *(ushort4*)&dh[el + 4] = h1;
    *(ushort4*)&dl[el] = l0;
    *(ushort4*)&dl[el + 4] = l1;
  }
}

__device__ __forceinline__ bf16x8 ldfrag(const unsigned short* s, int row, int k) {
  int el = (row * 128 + k) ^ ((row & 7) << 3);
  return *(const bf16x8*)&s[el];
}

// -------- Kernel 3: fused x-proj (MFMA bf16x3) + recurrent MFMA RNN --------
// One block per group of BM pairs of one expert. W_hh fragments in VGPRs,
// H double-buffered in swizzled LDS, x-projection chunked 8 steps at a time.
__global__ __launch_bounds__(256) void k_rnn(
    const float* __restrict__ x, const float* __restrict__ W_ih,
    const float* __restrict__ W_hh, const float* __restrict__ b_ih,
    const float* __restrict__ b_hh, const float* __restrict__ fc1_w,
    const float* __restrict__ fc1_b, const float* __restrict__ fc2_w,
    const float* __restrict__ fc2_b, const int* __restrict__ pair_b,
    const int* __restrict__ blk_e, const int* __restrict__ blk_p0,
    const int* __restrict__ blk_nr, const int* __restrict__ nblk,
    float* __restrict__ outp) {
  __shared__ unsigned short sWh[16384], sWl[16384];   // 64 KB
  __shared__ unsigned short sXh[8192], sXl[8192];     // 32 KB
  __shared__ unsigned short sHh[2][2048], sHl[2][2048]; // 16 KB
  __shared__ float sP[8192];                          // 32 KB
  __shared__ float sZ[BM * F_DIM];

  int blk = blockIdx.x;
  if (blk >= *nblk) return;
  int e = blk_e[blk], p0 = blk_p0[blk], nr = blk_nr[blk];
  int tid = threadIdx.x;
  int lane = tid & 63, g = lane >> 4, ln = lane & 15;
  int MT0 = (tid >> 6) * 2;  // 2 h-tiles owned by this wave

  // ---- stage W_hh, pull its fragments into registers ----
  stage_w(W_hh + (size_t)e * 16384, sWh, sWl, tid);
  __syncthreads();
  bf16x8 whh_h[2][4], whh_l[2][4];
#pragma unroll
  for (int mt = 0; mt < 2; mt++)
#pragma unroll
    for (int ks = 0; ks < 4; ks++) {
      int row = (MT0 + mt) * 16 + ln;
      whh_h[mt][ks] = ldfrag(sWh, row, ks * 32 + g * 8);
      whh_l[mt][ks] = ldfrag(sWl, row, ks * 32 + g * 8);
    }
  __syncthreads();
  // ---- stage W_ih into the same LDS buffers ----
  stage_w(W_ih + (size_t)e * 16384, sWh, sWl, tid);
  // zero both H buffers (rows >= BM stay zero forever)
#pragma unroll
  for (int it = 0; it < 8; it++) {
    int idx = tid + it * 256;
    sHh[0][idx] = 0; sHh[1][idx] = 0;
    sHl[0][idx] = 0; sHl[1][idx] = 0;
  }
  // biases (b_ih + b_hh), laid out to match C/D fragment rows
  f32x4 biasv[2];
#pragma unroll
  for (int mt = 0; mt < 2; mt++)
#pragma unroll
    for (int r = 0; r < 4; r++) {
      int h = (MT0 + mt) * 16 + g * 4 + r;
      biasv[mt][r] = b_ih[e * 128 + h] + b_hh[e * 128 + h];
    }
  // x prefetch setup: thread covers row n = tid>>2 (n = s_local*8 + r), 32 floats
  int xn = tid >> 2;
  int xk0 = (tid & 3) * 32;
  int xr_row = xn & 7;
  int xb_idx = pair_b[p0 + (xr_row < nr ? xr_row : 0)];
  const float* xsrc = x + (size_t)xb_idx * (S_SZ * 128) + (xn >> 3) * 128 + xk0;
  float4 xr[8];
#pragma unroll
  for (int j = 0; j < 8; j++) xr[j] = *(const float4*)(xsrc + j * 4);
  __syncthreads();

#pragma unroll 1
  for (int c = 0; c < 64; c++) {
    // write prefetched x chunk to swizzled LDS (hi/lo)
    {
      int sw = (xn & 7) << 3;
#pragma unroll
      for (int j = 0; j < 8; j++) {
        int el = (xn * 128 + xk0 + j * 4) ^ sw;
        ushort4 hi, lo;
        cvt4(xr[j], &hi, &lo);
        *(ushort4*)&sXh[el] = hi;
        *(ushort4*)&sXl[el] = lo;
      }
    }
    __syncthreads();
    // ---- x-projection for this chunk: P[n= s*8+r][h] = x.W_ih^T + biases ----
#pragma unroll
    for (int mt = 0; mt < 2; mt++) {
      bf16x8 Ah[4], Al[4];
#pragma unroll
      for (int ks = 0; ks < 4; ks++) {
        int row = (MT0 + mt) * 16 + ln;
        Ah[ks] = ldfrag(sWh, row, ks * 32 + g * 8);
        Al[ks] = ldfrag(sWl, row, ks * 32 + g * 8);
      }
#pragma unroll
      for (int nt = 0; nt < 4; nt++) {
        bf16x8 Bh[4], Bl[4];
#pragma unroll
        for (int ks = 0; ks < 4; ks++) {
          int row = nt * 16 + ln;
          Bh[ks] = ldfrag(sXh, row, ks * 32 + g * 8);
          Bl[ks] = ldfrag(sXl, row, ks * 32 + g * 8);
        }
        f32x4 a0 = {0.f, 0.f, 0.f, 0.f}, a1 = {0.f, 0.f, 0.f, 0.f};
#pragma unroll
        for (int ks = 0; ks < 4; ks++) {
          a0 = MFMA(Ah[ks], Bh[ks], a0);
          a1 = MFMA(Al[ks], Bh[ks], a1);
          a0 = MFMA(Ah[ks], Bl[ks], a0);
        }
        f32x4 p = a0 + a1 + biasv[mt];
        int n = nt * 16 + ln;
        int el = (n * 128 + (MT0 + mt) * 16 + g * 4) ^ ((n & 7) << 2);
        *(f32x4*)&sP[el] = p;
      }
    }
    // prefetch next chunk's x while recurrent steps run
    if (c < 63) {
#pragma unroll
      for (int j = 0; j < 8; j++)
        xr[j] = *(const float4*)(xsrc + (c + 1) * 1024 + j * 4);
    }
    __syncthreads();
    // ---- 8 recurrent steps ----
#pragma unroll 1
    for (int s = 0; s < 8; s++) {
      int rb = s & 1;
      bf16x8 Hh[4], Hl[4];
#pragma unroll
      for (int ks = 0; ks < 4; ks++) {
        Hh[ks] = ldfrag(sHh[rb], ln, ks * 32 + g * 8);
        Hl[ks] = ldfrag(sHl[rb], ln, ks * 32 + g * 8);
      }
      f32x4 pre[2];
#pragma unroll
      for (int mt = 0; mt < 2; mt++) {
        int rr = ln & 7;
        int pel = ((s * 8 + rr) * 128 + (MT0 + mt) * 16 + g * 4) ^ (rr << 2);
        f32x4 a0 = *(const f32x4*)&sP[pel];
        f32x4 a1 = {0.f, 0.f, 0.f, 0.f};
#pragma unroll
        for (int ks = 0; ks < 4; ks++) {
          a0 = MFMA(whh_h[mt][ks], Hh[ks], a0);
          a1 = MFMA(whh_l[mt][ks], Hh[ks], a1);
          a1 = MFMA(whh_h[mt][ks], Hl[ks], a1);
        }
        pre[mt] = a0 + a1;
      }
      if (ln < BM) {
#pragma unroll
        for (int mt = 0; mt < 2; mt++) {
          float t0 = tanhf(pre[mt][0]);
          float t1 = tanhf(pre[mt][1]);
          float t2 = tanhf(pre[mt][2]);
          float t3 = tanhf(pre[mt][3]);
          ushort4 hi, lo;
          float4 tv = {t0, t1, t2, t3};
          cvt4(tv, &hi, &lo);
          int el = (ln * 128 + (MT0 + mt) * 16 + g * 4) ^ (ln << 3);
          *(ushort4*)&sHh[rb ^ 1][el] = hi;
          *(ushort4*)&sHl[rb ^ 1][el] = lo;
        }
      }
      __syncthreads();
    }
  }
  // ---- MLP head: z = tanh(hT.fc1^T + b1); out = z.fc2^T + b2 ----
  if (tid < BM * F_DIM) {
    int r = tid / F_DIM, f = tid % F_DIM;
    float acc = fc1_b[e * F_DIM + f];
    const float* w1 = fc1_w + (size_t)e * (F_DIM * 128) + f * 128;
    for (int k = 0; k < 128; k++) {
      int el = (r * 128 + k) ^ ((r & 7) << 3);
      float h = bf2f(sHh[0][el]) + bf2f(sHl[0][el]);
      acc += h * w1[k];
    }
    sZ[r * F_DIM + f] = tanhf(acc);
  }
  __syncthreads();
  if (tid < BM) {
    int r = tid;
    float acc = fc2_b[e];
#pragma unroll
    for (int f = 0; f < F_DIM; f++) acc += sZ[r * F_DIM + f] * fc2_w[e * F_DIM + f];
    if (r < nr) outp[p0 + r] = acc;
  }
}

// ---------------- Kernel 4: weighted combine ----------------
__global__ void k_combine(const float* __restrict__ sel_g,
                          const int* __restrict__ pair_of,
                          const float* __restrict__ outp,
                          float* __restrict__ y) {
  int b = blockIdx.x * blockDim.x + threadIdx.x;
  if (b < B_SZ)
    y[b] = sel_g[2 * b] * outp[pair_of[2 * b]] +
           sel_g[2 * b + 1] * outp[pair_of[2 * b + 1]];
}

extern "C" void kernel_launch(void* const* d_in, const int* in_sizes, int n_in,
                              void* d_out, int out_size, void* d_ws,
                              size_t ws_size, hipStream_t stream) {
  (void)in_sizes; (void)n_in; (void)out_size; (void)ws_size;
  const float* x      = (const float*)d_in[0];
  const float* w_gate = (const float*)d_in[1];
  const float* W_ih   = (const float*)d_in[2];
  const float* W_hh   = (const float*)d_in[3];
  const float* b_ih   = (const float*)d_in[4];
  const float* b_hh   = (const float*)d_in[5];
  const float* fc1_w  = (const float*)d_in[6];
  const float* fc1_b  = (const float*)d_in[7];
  const float* fc2_w  = (const float*)d_in[8];
  const float* fc2_b  = (const float*)d_in[9];
  float* out = (float*)d_out;  // [0..511] = y, [512] = loss

  float* logits = (float*)d_ws;            // 4096 f32
  float* sel_g  = logits + 4096;           // 1024 f32
  int*   pair_b = (int*)(sel_g + 1024);    // 1024 i32
  int*   pair_of= pair_b + 1024;           // 1024 i32
  int*   blk_e  = pair_of + 1024;          // 160 i32
  int*   blk_p0 = blk_e + 160;             // 160 i32
  int*   blk_nr = blk_p0 + 160;            // 160 i32
  int*   nblk   = blk_nr + 160;            // 1 i32
  float* outp   = (float*)(nblk + 4);      // 1024 f32

  k_mean_logits<<<B_SZ, 512, 0, stream>>>(x, w_gate, logits);
  k_gate<<<1, 512, 0, stream>>>(logits, sel_g, pair_b, pair_of, blk_e, blk_p0,
                                blk_nr, nblk, out + 512);
  k_rnn<<<MAXBLK, 256, 0, stream>>>(x, W_ih, W_hh, b_ih, b_hh, fc1_w, fc1_b,
                                    fc2_w, fc2_b, pair_b, blk_e, blk_p0,
                                    blk_nr, nblk, outp);
  k_combine<<<2, 256, 0, stream>>>(sel_g, pair_of, outp, out);
}